// Round 11
// baseline (123.824 us; speedup 1.0000x reference)
//
#include <hip/hip_runtime.h>
#include <math.h>

// Problem constants
#define T_LEN 512
#define DF 64
#define ROW_ELEMS (T_LEN * DF)   // 32768 floats per row
#define STEP_ 16
#define NROWS_G 44               // 4 groups * 11 rows
#define GSTRIDE (NROWS_G * DF)   // 2816
#define MAGIC 0x13579BDFu        // != 0xAAAAAAAA ws-poison

// pairs = [(i,j) for i in range(4) for j in range(1,4) if i != j] -> 9 pairs
__constant__ int c_PI[9] = {0, 0, 0, 1, 1, 2, 2, 3, 3};
__constant__ int c_PJ[9] = {1, 2, 3, 2, 3, 1, 3, 1, 2};

// block-wide sum via wave shuffle + 4-slot LDS (two syncthreads); 256 threads
__device__ inline float blockSum(float v, float* tmp4) {
    #pragma unroll
    for (int off = 32; off > 0; off >>= 1) v += __shfl_down(v, off);
    if ((threadIdx.x & 63) == 0) tmp4[threadIdx.x >> 6] = v;
    __syncthreads();
    const float s = tmp4[0] + tmp4[1] + tmp4[2] + tmp4[3];
    __syncthreads();
    return s;
}

__device__ inline void waitFlag(unsigned* f) {
    while (atomicAdd(f, 0u) != MAGIC) __builtin_amdgcn_s_sleep(1);
}

// ---------------------------------------------------------------------------
// k_fused, 252 blocks x 256 threads (all co-resident: 252 <= 256 CUs).
// Phase 1:
//   blocks [0,132):  gram tiles split over t: (tile, t-half); float4 loads;
//                    G_half[a,b,d] = sum_{t in half} Za[t,d]*Zb[t,d]
//   blocks [132,252): sd[p] = sum_t ||X[p,t]-Y[p,t]||^2 (softdtw collapses to
//                    the diagonal: BANDWIDTH=0.1 keeps only i==j)
//   each block: stores -> syncthreads -> threadfence -> flag1[b]=MAGIC
// Phase 2 (blocks [0,198)): wait gram flags, fence, MMD row (bw redundant per
//   block from L2/L3-hot G), partial[b] -> flag2[b].
// Block 251: waits all flags, fence, triplet finisher + mmd max -> out[0].
// ---------------------------------------------------------------------------
__global__ __launch_bounds__(256) void k_fused(
    const float* __restrict__ data, const float* __restrict__ teacher,
    const int* __restrict__ lens,
    float* __restrict__ sd,      // 120
    float* __restrict__ G0,      // 44*44*64
    float* __restrict__ G1,      // 44*44*64
    float* __restrict__ partial, // 198 (pad 256)
    unsigned* __restrict__ flag1,// 252 (pad 256)
    unsigned* __restrict__ flag2,// 198 (pad 256)
    float* __restrict__ out)
{
    const int b = blockIdx.x;
    const int tid = threadIdx.x;

    __shared__ float red2[16][16][DF];   // 64 KB (gram)
    __shared__ float redS[256];          // 1 KB  (sd)
    __shared__ float diagT[22 * DF];     // 5.5 KB (mmd)
    __shared__ float tmp4[4];
    __shared__ float fin[256];
    __shared__ float mmd9[9];
    __shared__ float sdl[120];

    // ======================= phase 1 =======================
    if (b < 132) {
        const int tile = b >> 1, half = b & 1;
        int q = tile, ta = 0;
        while (q >= 11 - ta) { q -= 11 - ta; ta++; }
        const int tb = ta + q;
        const int ty = tid >> 4, dq = tid & 15;     // 16x16 threads
        const int ua0 = ta * 4, ub0 = tb * 4;

        const float4* rA[4];
        const float4* rB[4];
        #pragma unroll
        for (int i = 0; i < 4; ++i) {
            const int ua = ua0 + i, ub = ub0 + i;
            rA[i] = (const float4*)(data + (size_t)((ua / 11) * STEP_ + (ua % 11)) * ROW_ELEMS);
            rB[i] = (const float4*)(data + (size_t)((ub / 11) * STEP_ + (ub % 11)) * ROW_ELEMS);
        }

        float acc[4][4][4];
        #pragma unroll
        for (int i = 0; i < 4; ++i)
            #pragma unroll
            for (int j = 0; j < 4; ++j)
                #pragma unroll
                for (int c = 0; c < 4; ++c) acc[i][j][c] = 0.f;

        const int tbase = half * 256 + ty;           // t-half, stride 16
        #pragma unroll 2
        for (int it = 0; it < 16; ++it) {
            const int t = tbase + it * 16;
            float4 av[4], bv[4];
            #pragma unroll
            for (int i = 0; i < 4; ++i) av[i] = rA[i][t * 16 + dq];
            #pragma unroll
            for (int j = 0; j < 4; ++j) bv[j] = rB[j][t * 16 + dq];
            #pragma unroll
            for (int i = 0; i < 4; ++i)
                #pragma unroll
                for (int j = 0; j < 4; ++j) {
                    acc[i][j][0] += av[i].x * bv[j].x;
                    acc[i][j][1] += av[i].y * bv[j].y;
                    acc[i][j][2] += av[i].z * bv[j].z;
                    acc[i][j][3] += av[i].w * bv[j].w;
                }
        }

        #pragma unroll
        for (int i = 0; i < 4; ++i)
            #pragma unroll
            for (int j = 0; j < 4; ++j)
                *(float4*)&red2[ty][i * 4 + j][dq * 4] =
                    make_float4(acc[i][j][0], acc[i][j][1], acc[i][j][2], acc[i][j][3]);
        __syncthreads();

        float* __restrict__ Gh = half ? G1 : G0;
        for (int o = tid; o < 1024; o += 256) {
            const int ij = o >> 6, d = o & 63;
            float s = 0.f;
            #pragma unroll
            for (int t2 = 0; t2 < 16; ++t2) s += red2[t2][ij][d];
            const int ua = ua0 + (ij >> 2), ub = ub0 + (ij & 3);
            Gh[(size_t)ua * GSTRIDE + ub * DF + d] = s;
            Gh[(size_t)ub * GSTRIDE + ua * DF + d] = s;   // same value on diag tiles
        }
    } else {
        const int bb = b - 132;                  // 0..119
        const float* src = (bb < 60) ? data : teacher;
        const int p = bb % 60;
        const int w = p / 15, k = p % 15;
        const float4* A = (const float4*)(src + (size_t)(w * STEP_) * ROW_ELEMS);
        const float4* O = (const float4*)(src + (size_t)(w * STEP_ + 1 + k) * ROW_ELEMS);
        float acc = 0.f;
        #pragma unroll 4
        for (int i = tid; i < ROW_ELEMS / 4; i += 256) {
            float4 a = A[i], o = O[i];
            float dx = a.x - o.x, dy = a.y - o.y, dz = a.z - o.z, dw = a.w - o.w;
            acc += dx * dx + dy * dy + dz * dz + dw * dw;
        }
        redS[tid] = acc;
        __syncthreads();
        for (int s = 128; s > 0; s >>= 1) {
            if (tid < s) redS[tid] += redS[tid + s];
            __syncthreads();
        }
        if (tid == 0) sd[bb] = redS[0];
    }

    // release: all block stores drained at syncthreads; wb + flag
    __syncthreads();
    if (tid == 0) { __threadfence(); atomicExch(&flag1[b], MAGIC); }

    if (b >= 198 && b != 251) return;

    if (b < 198) {
        // ======================= phase 2: MMD row =======================
        if (tid < 132) waitFlag(&flag1[tid]);   // gram blocks done
        __syncthreads();
        __threadfence();                        // acquire: invalidate stale L2

        const int p = b / 22, aa = b % 22;
        const int gi = c_PI[p], gj = c_PJ[p];

        // Phase A: diag rows (summed halves) into LDS
        for (int e = tid; e < 22 * DF; e += 256) {
            const int bb = e >> 6, d2 = e & 63;
            const int ub = (bb < 11) ? gi * 11 + bb : gj * 11 + bb - 11;
            const size_t off = (size_t)ub * GSTRIDE + ub * DF + d2;
            diagT[e] = G0[off] + G1[off];
        }

        // full-pair gram sum: 22 rows x 2 contiguous 11*64-float spans
        const float4* G0q = (const float4*)G0;
        const float4* G1q = (const float4*)G1;
        float gs = 0.f;
        for (int e = tid; e < 7744; e += 256) {
            const int f4 = e % 176;
            const int sp = (e / 176) & 1;
            const int a2 = e / 352;
            const int ua = (a2 < 11) ? gi * 11 + a2 : gj * 11 + a2 - 11;
            const int colbase = (sp ? gj : gi) * 11 * DF;
            const size_t qi = ((size_t)ua * GSTRIDE + colbase) / 4 + f4;
            const float4 v0 = G0q[qi], v1 = G1q[qi];
            gs += (v0.x + v1.x) + (v0.y + v1.y) + (v0.z + v1.z) + (v0.w + v1.w);
        }
        __syncthreads();   // diagT ready

        float dsp = 0.f;
        for (int e = tid; e < 22 * DF; e += 256) dsp += diagT[e];

        const float sumG    = blockSum(gs,  tmp4);
        const float diagSum = blockSum(dsp, tmp4);

        const float bw = (44.f * diagSum - 2.f * sumG) / (462.f * 4.f);
        const float inv0 = 1.f / bw;

        // Phase B: signed kernel sum for row aa (float4 over d)
        const int ua = (aa < 11) ? gi * 11 + aa : gj * 11 + aa - 11;
        const bool sa = (aa < 11);
        const float4* cr0 = (const float4*)(G0 + (size_t)ua * GSTRIDE);
        const float4* cr1 = (const float4*)(G1 + (size_t)ua * GSTRIDE);
        const float4* dTq = (const float4*)diagT;

        float s2 = 0.f;
        for (int e = tid; e < 22 * 16; e += 256) {
            const int bb = e >> 4, dq = e & 15;
            const int ub = (bb < 11) ? gi * 11 + bb : gj * 11 + bb - 11;
            const float4 c0 = cr0[ub * 16 + dq], c1 = cr1[ub * 16 + dq];
            const float4 dB = dTq[e];
            const float4 dA = dTq[aa * 16 + dq];
            float l2[4];
            l2[0] = dA.x + dB.x - 2.f * (c0.x + c1.x);
            l2[1] = dA.y + dB.y - 2.f * (c0.y + c1.y);
            l2[2] = dA.z + dB.z - 2.f * (c0.z + c1.z);
            l2[3] = dA.w + dB.w - 2.f * (c0.w + c1.w);
            float kv = 0.f;
            #pragma unroll
            for (int c = 0; c < 4; ++c) {
                float inv = inv0;
                #pragma unroll
                for (int ii = 0; ii < 5; ++ii) { kv += __expf(-l2[c] * inv); inv *= 0.5f; }
            }
            s2 += ((bb < 11) == sa) ? kv : -kv;
        }
        const float rowSum = blockSum(s2, tmp4);

        if (tid == 0) {
            partial[b] = rowSum;
            __threadfence();
            atomicExch(&flag2[b], MAGIC);
        }
        return;
    }

    // ======================= b == 251: finisher =======================
    if (tid < 252) waitFlag(&flag1[tid]);   // sd writers (and gram) done
    if (tid < 198) waitFlag(&flag2[tid]);   // all MMD rows done
    __syncthreads();
    __threadfence();                        // acquire

    fin[tid] = (tid < 198) ? partial[tid] : 0.f;
    if (tid < 120) sdl[tid] = sd[tid];
    __syncthreads();

    if (tid < 9) {
        float s = 0.f;
        #pragma unroll
        for (int k2 = 0; k2 < 22; ++k2) s += fin[tid * 22 + k2];
        mmd9[tid] = s / (121.f * 64.f);
    }
    __syncthreads();

    if (tid == 0) {
        float total = 0.f;
        for (int w = 0; w < 4; ++w) {
            float ds[15], dt[15];
            for (int k = 0; k < 15; ++k) {
                const float denom = (float)lens[w * STEP_] + (float)lens[w * STEP_ + 1 + k];
                ds[k] = sdl[w * 15 + k] / denom;
                dt[k] = sdl[60 + w * 15 + k] / denom;
            }
            float mx = 0.f;
            for (int i = 0; i < 10; ++i)
                for (int j = 0; j < 5; ++j) {
                    float v = dt[5 + i] - dt[j];
                    v = v > 0.f ? v : 0.f;
                    mx = fmaxf(mx, v);
                }
            const float scale = (1.0f - 0.1f) / mx;
            float sum_lk = 0.f, nz = 0.f;
            for (int i = 0; i < 10; ++i)
                for (int j = 0; j < 5; ++j) {
                    float v = dt[5 + i] - dt[j];
                    v = v > 0.f ? v : 0.f;
                    const float fd = scale * v + 0.1f;
                    float lk = ds[j] - ds[5 + i] + fd;
                    lk = lk > 0.f ? lk : 0.f;
                    sum_lk += lk;
                    if (lk != 0.f) nz += 1.f;
                }
            const float lv = sum_lk / (nz + 1.f);
            const float ca = (ds[0] + ds[1] + ds[2] + ds[3] + ds[4]) * 0.2f;
            const float cb = (ds[5] + ds[6] + ds[7] + ds[8] + ds[9]) * 0.2f;
            const float intra = (ds[0] - ca) + (ds[1] - ca) + (ds[2] - ca) + (ds[3] - ca) + (ds[4] - ca);
            float inter = 1.0f - fabsf(ca - cb);
            inter = inter > 0.f ? inter : 0.f;
            total += lv + intra * 0.1f + inter * 0.1f;
        }
        total *= 0.25f;

        float mmax = 0.f;   // padded zero slot in mmds
        for (int q2 = 0; q2 < 9; ++q2) mmax = fmaxf(mmax, mmd9[q2]);
        out[0] = total + 0.5f * mmax;
    }
}

// ---------------------------------------------------------------------------
extern "C" void kernel_launch(void* const* d_in, const int* in_sizes, int n_in,
                              void* d_out, int out_size, void* d_ws, size_t ws_size,
                              hipStream_t stream) {
    const float* data    = (const float*)d_in[0];
    const int*   lens    = (const int*)d_in[1];
    const float* teacher = (const float*)d_in[2];
    float* out = (float*)d_out;

    float*    sd      = (float*)d_ws;                    // 120 (pad 128)
    float*    G0      = sd + 128;                        // 123904
    float*    G1      = G0 + (size_t)NROWS_G * GSTRIDE;  // 123904
    float*    partial = G1 + (size_t)NROWS_G * GSTRIDE;  // 198 (pad 256)
    unsigned* flag1   = (unsigned*)(partial + 256);      // 252 (pad 256)
    unsigned* flag2   = flag1 + 256;                     // 198 (pad 256)

    k_fused<<<252, 256, 0, stream>>>(data, teacher, lens, sd, G0, G1,
                                     partial, flag1, flag2, out);
}

// Round 13
// 120.103 us; speedup vs baseline: 1.0310x; 1.0310x over previous
//
#include <hip/hip_runtime.h>
#include <math.h>

// Problem constants
#define T_LEN 512
#define DF 64
#define ROW_ELEMS (T_LEN * DF)   // 32768 floats per row
#define STEP_ 16
#define NROWS_G 44               // 4 groups * 11 rows
#define GSTRIDE (NROWS_G * DF)   // 2816
#define MAGIC 0x13579BDFu        // != 0xAAAAAAAA ws-poison

// pairs = [(i,j) for i in range(4) for j in range(1,4) if i != j] -> 9 pairs
__constant__ int c_PI[9] = {0, 0, 0, 1, 1, 2, 2, 3, 3};
__constant__ int c_PJ[9] = {1, 2, 3, 2, 3, 1, 3, 1, 2};

// block-wide sum via wave shuffle + 4-slot LDS (two syncthreads); 256 threads
__device__ inline float blockSum(float v, float* tmp4) {
    #pragma unroll
    for (int off = 32; off > 0; off >>= 1) v += __shfl_down(v, off);
    if ((threadIdx.x & 63) == 0) tmp4[threadIdx.x >> 6] = v;
    __syncthreads();
    const float s = tmp4[0] + tmp4[1] + tmp4[2] + tmp4[3];
    __syncthreads();
    return s;
}

// poll with relaxed agent-scope atomic LOAD (no RMW -> no serialization)
__device__ inline void waitFlag(unsigned* f) {
    while (__hip_atomic_load(f, __ATOMIC_RELAXED, __HIP_MEMORY_SCOPE_AGENT) != MAGIC)
        __builtin_amdgcn_s_sleep(1);
}
__device__ inline void setFlag(unsigned* f) {
    __threadfence();   // release: drain/flush this block's stores
    __hip_atomic_store(f, MAGIC, __ATOMIC_RELAXED, __HIP_MEMORY_SCOPE_AGENT);
}
__device__ inline float loadF(float* p) {
    return __hip_atomic_load(p, __ATOMIC_RELAXED, __HIP_MEMORY_SCOPE_AGENT);
}

// ---------------------------------------------------------------------------
// k_fused, 252 blocks x 256 threads (all co-resident: 252 <= 256 CUs).
// Phase 1:
//   blocks [0,132):  gram tiles split over t: (tile, t-half); float4 loads;
//                    G_half[a,b,d] = sum_{t in half} Za[t,d]*Zb[t,d]
//   blocks [132,252): sd[p] = sum_t ||X[p,t]-Y[p,t]||^2 (softdtw collapses to
//                    the diagonal: BANDWIDTH=0.1 keeps only i==j)
//   each block: stores -> syncthreads -> threadfence -> flag1[b]=MAGIC
// Phase 2 (blocks [0,198)): wait gram flags (atomic loads), fence, MMD row
//   (bw redundant per block from L2/L3-hot G), partial[b] -> flag2[b].
// Block 251: waits all flags, fence, triplet finisher + mmd max -> out[0].
// ---------------------------------------------------------------------------
__global__ __launch_bounds__(256) void k_fused(
    const float* __restrict__ data, const float* __restrict__ teacher,
    const int* __restrict__ lens,
    float* __restrict__ sd,      // 120
    float* __restrict__ G0,      // 44*44*64
    float* __restrict__ G1,      // 44*44*64
    float* __restrict__ partial, // 198 (pad 256)
    unsigned* __restrict__ flag1,// 252 (pad 256)
    unsigned* __restrict__ flag2,// 198 (pad 256)
    float* __restrict__ out)
{
    const int b = blockIdx.x;
    const int tid = threadIdx.x;

    __shared__ float red2[16][16][DF];   // 64 KB (gram)
    __shared__ float redS[256];          // 1 KB  (sd)
    __shared__ float diagT[22 * DF];     // 5.5 KB (mmd)
    __shared__ float tmp4[4];
    __shared__ float fin[256];
    __shared__ float mmd9[9];
    __shared__ float sdl[120];

    // ======================= phase 1 =======================
    if (b < 132) {
        const int tile = b >> 1, half = b & 1;
        int q = tile, ta = 0;
        while (q >= 11 - ta) { q -= 11 - ta; ta++; }
        const int tb = ta + q;
        const int ty = tid >> 4, dq = tid & 15;     // 16x16 threads
        const int ua0 = ta * 4, ub0 = tb * 4;

        const float4* rA[4];
        const float4* rB[4];
        #pragma unroll
        for (int i = 0; i < 4; ++i) {
            const int ua = ua0 + i, ub = ub0 + i;
            rA[i] = (const float4*)(data + (size_t)((ua / 11) * STEP_ + (ua % 11)) * ROW_ELEMS);
            rB[i] = (const float4*)(data + (size_t)((ub / 11) * STEP_ + (ub % 11)) * ROW_ELEMS);
        }

        float acc[4][4][4];
        #pragma unroll
        for (int i = 0; i < 4; ++i)
            #pragma unroll
            for (int j = 0; j < 4; ++j)
                #pragma unroll
                for (int c = 0; c < 4; ++c) acc[i][j][c] = 0.f;

        const int tbase = half * 256 + ty;           // t-half, stride 16
        #pragma unroll 2
        for (int it = 0; it < 16; ++it) {
            const int t = tbase + it * 16;
            float4 av[4], bv[4];
            #pragma unroll
            for (int i = 0; i < 4; ++i) av[i] = rA[i][t * 16 + dq];
            #pragma unroll
            for (int j = 0; j < 4; ++j) bv[j] = rB[j][t * 16 + dq];
            #pragma unroll
            for (int i = 0; i < 4; ++i)
                #pragma unroll
                for (int j = 0; j < 4; ++j) {
                    acc[i][j][0] += av[i].x * bv[j].x;
                    acc[i][j][1] += av[i].y * bv[j].y;
                    acc[i][j][2] += av[i].z * bv[j].z;
                    acc[i][j][3] += av[i].w * bv[j].w;
                }
        }

        #pragma unroll
        for (int i = 0; i < 4; ++i)
            #pragma unroll
            for (int j = 0; j < 4; ++j)
                *(float4*)&red2[ty][i * 4 + j][dq * 4] =
                    make_float4(acc[i][j][0], acc[i][j][1], acc[i][j][2], acc[i][j][3]);
        __syncthreads();

        float* __restrict__ Gh = half ? G1 : G0;
        for (int o = tid; o < 1024; o += 256) {
            const int ij = o >> 6, d = o & 63;
            float s = 0.f;
            #pragma unroll
            for (int t2 = 0; t2 < 16; ++t2) s += red2[t2][ij][d];
            const int ua = ua0 + (ij >> 2), ub = ub0 + (ij & 3);
            Gh[(size_t)ua * GSTRIDE + ub * DF + d] = s;
            Gh[(size_t)ub * GSTRIDE + ua * DF + d] = s;   // same value on diag tiles
        }
    } else {
        const int bb = b - 132;                  // 0..119
        const float* src = (bb < 60) ? data : teacher;
        const int p = bb % 60;
        const int w = p / 15, k = p % 15;
        const float4* A = (const float4*)(src + (size_t)(w * STEP_) * ROW_ELEMS);
        const float4* O = (const float4*)(src + (size_t)(w * STEP_ + 1 + k) * ROW_ELEMS);
        float acc = 0.f;
        #pragma unroll 4
        for (int i = tid; i < ROW_ELEMS / 4; i += 256) {
            float4 a = A[i], o = O[i];
            float dx = a.x - o.x, dy = a.y - o.y, dz = a.z - o.z, dw = a.w - o.w;
            acc += dx * dx + dy * dy + dz * dz + dw * dw;
        }
        redS[tid] = acc;
        __syncthreads();
        for (int s = 128; s > 0; s >>= 1) {
            if (tid < s) redS[tid] += redS[tid + s];
            __syncthreads();
        }
        if (tid == 0) sd[bb] = redS[0];
    }

    // release: all block stores drained at syncthreads; fence + flag store
    __syncthreads();
    if (tid == 0) setFlag(&flag1[b]);

    if (b >= 198 && b != 251) return;

    if (b < 198) {
        // ======================= phase 2: MMD row =======================
        if (tid < 132) waitFlag(&flag1[tid]);   // gram blocks done
        __syncthreads();
        __threadfence();                        // acquire: invalidate stale caches

        const int p = b / 22, aa = b % 22;
        const int gi = c_PI[p], gj = c_PJ[p];

        // Phase A: diag rows (summed halves) into LDS
        for (int e = tid; e < 22 * DF; e += 256) {
            const int bb = e >> 6, d2 = e & 63;
            const int ub = (bb < 11) ? gi * 11 + bb : gj * 11 + bb - 11;
            const size_t off = (size_t)ub * GSTRIDE + ub * DF + d2;
            diagT[e] = G0[off] + G1[off];
        }

        // full-pair gram sum: 22 rows x 2 contiguous 11*64-float spans
        const float4* G0q = (const float4*)G0;
        const float4* G1q = (const float4*)G1;
        float gs = 0.f;
        for (int e = tid; e < 7744; e += 256) {
            const int f4 = e % 176;
            const int sp = (e / 176) & 1;
            const int a2 = e / 352;
            const int ua = (a2 < 11) ? gi * 11 + a2 : gj * 11 + a2 - 11;
            const int colbase = (sp ? gj : gi) * 11 * DF;
            const size_t qi = ((size_t)ua * GSTRIDE + colbase) / 4 + f4;
            const float4 v0 = G0q[qi], v1 = G1q[qi];
            gs += (v0.x + v1.x) + (v0.y + v1.y) + (v0.z + v1.z) + (v0.w + v1.w);
        }
        __syncthreads();   // diagT ready

        float dsp = 0.f;
        for (int e = tid; e < 22 * DF; e += 256) dsp += diagT[e];

        const float sumG    = blockSum(gs,  tmp4);
        const float diagSum = blockSum(dsp, tmp4);

        const float bw = (44.f * diagSum - 2.f * sumG) / (462.f * 4.f);
        const float inv0 = 1.f / bw;

        // Phase B: signed kernel sum for row aa (float4 over d)
        const int ua = (aa < 11) ? gi * 11 + aa : gj * 11 + aa - 11;
        const bool sa = (aa < 11);
        const float4* cr0 = (const float4*)(G0 + (size_t)ua * GSTRIDE);
        const float4* cr1 = (const float4*)(G1 + (size_t)ua * GSTRIDE);
        const float4* dTq = (const float4*)diagT;

        float s2 = 0.f;
        for (int e = tid; e < 22 * 16; e += 256) {
            const int bb = e >> 4, dq = e & 15;
            const int ub = (bb < 11) ? gi * 11 + bb : gj * 11 + bb - 11;
            const float4 c0 = cr0[ub * 16 + dq], c1 = cr1[ub * 16 + dq];
            const float4 dB = dTq[e];
            const float4 dA = dTq[aa * 16 + dq];
            float l2[4];
            l2[0] = dA.x + dB.x - 2.f * (c0.x + c1.x);
            l2[1] = dA.y + dB.y - 2.f * (c0.y + c1.y);
            l2[2] = dA.z + dB.z - 2.f * (c0.z + c1.z);
            l2[3] = dA.w + dB.w - 2.f * (c0.w + c1.w);
            float kv = 0.f;
            #pragma unroll
            for (int c = 0; c < 4; ++c) {
                float inv = inv0;
                #pragma unroll
                for (int ii = 0; ii < 5; ++ii) { kv += __expf(-l2[c] * inv); inv *= 0.5f; }
            }
            s2 += ((bb < 11) == sa) ? kv : -kv;
        }
        const float rowSum = blockSum(s2, tmp4);

        if (tid == 0) {
            partial[b] = rowSum;
            setFlag(&flag2[b]);
        }
        return;
    }

    // ======================= b == 251: finisher =======================
    if (tid < 252) waitFlag(&flag1[tid]);   // sd writers (and gram) done
    if (tid < 198) waitFlag(&flag2[tid]);   // all MMD rows done
    __syncthreads();
    __threadfence();                        // acquire

    fin[tid] = (tid < 198) ? loadF(&partial[tid]) : 0.f;
    if (tid < 120) sdl[tid] = loadF(&sd[tid]);
    __syncthreads();

    if (tid < 9) {
        float s = 0.f;
        #pragma unroll
        for (int k2 = 0; k2 < 22; ++k2) s += fin[tid * 22 + k2];
        mmd9[tid] = s / (121.f * 64.f);
    }
    __syncthreads();

    if (tid == 0) {
        float total = 0.f;
        for (int w = 0; w < 4; ++w) {
            float ds[15], dt[15];
            for (int k = 0; k < 15; ++k) {
                const float denom = (float)lens[w * STEP_] + (float)lens[w * STEP_ + 1 + k];
                ds[k] = sdl[w * 15 + k] / denom;
                dt[k] = sdl[60 + w * 15 + k] / denom;
            }
            float mx = 0.f;
            for (int i = 0; i < 10; ++i)
                for (int j = 0; j < 5; ++j) {
                    float v = dt[5 + i] - dt[j];
                    v = v > 0.f ? v : 0.f;
                    mx = fmaxf(mx, v);
                }
            const float scale = (1.0f - 0.1f) / mx;
            float sum_lk = 0.f, nz = 0.f;
            for (int i = 0; i < 10; ++i)
                for (int j = 0; j < 5; ++j) {
                    float v = dt[5 + i] - dt[j];
                    v = v > 0.f ? v : 0.f;
                    const float fd = scale * v + 0.1f;
                    float lk = ds[j] - ds[5 + i] + fd;
                    lk = lk > 0.f ? lk : 0.f;
                    sum_lk += lk;
                    if (lk != 0.f) nz += 1.f;
                }
            const float lv = sum_lk / (nz + 1.f);
            const float ca = (ds[0] + ds[1] + ds[2] + ds[3] + ds[4]) * 0.2f;
            const float cb = (ds[5] + ds[6] + ds[7] + ds[8] + ds[9]) * 0.2f;
            const float intra = (ds[0] - ca) + (ds[1] - ca) + (ds[2] - ca) + (ds[3] - ca) + (ds[4] - ca);
            float inter = 1.0f - fabsf(ca - cb);
            inter = inter > 0.f ? inter : 0.f;
            total += lv + intra * 0.1f + inter * 0.1f;
        }
        total *= 0.25f;

        float mmax = 0.f;   // padded zero slot in mmds
        for (int q2 = 0; q2 < 9; ++q2) mmax = fmaxf(mmax, mmd9[q2]);
        out[0] = total + 0.5f * mmax;
    }
}

// ---------------------------------------------------------------------------
extern "C" void kernel_launch(void* const* d_in, const int* in_sizes, int n_in,
                              void* d_out, int out_size, void* d_ws, size_t ws_size,
                              hipStream_t stream) {
    const float* data    = (const float*)d_in[0];
    const int*   lens    = (const int*)d_in[1];
    const float* teacher = (const float*)d_in[2];
    float* out = (float*)d_out;

    float*    sd      = (float*)d_ws;                    // 120 (pad 128)
    float*    G0      = sd + 128;                        // 123904
    float*    G1      = G0 + (size_t)NROWS_G * GSTRIDE;  // 123904
    float*    partial = G1 + (size_t)NROWS_G * GSTRIDE;  // 198 (pad 256)
    unsigned* flag1   = (unsigned*)(partial + 256);      // 252 (pad 256)
    unsigned* flag2   = flag1 + 256;                     // 198 (pad 256)

    k_fused<<<252, 256, 0, stream>>>(data, teacher, lens, sd, G0, G1,
                                     partial, flag1, flag2, out);
}

// Round 15
// 99.314 us; speedup vs baseline: 1.2468x; 1.2093x over previous
//
#include <hip/hip_runtime.h>
#include <math.h>

// Problem constants
#define T_LEN 512
#define DF 64
#define ROW_ELEMS (T_LEN * DF)   // 32768 floats per row
#define STEP_ 16
#define NROWS_G 44               // 4 groups * 11 rows
#define GSTRIDE (NROWS_G * DF)   // 2816

// pairs = [(i,j) for i in range(4) for j in range(1,4) if i != j] -> 9 pairs
__constant__ int c_PI[9] = {0, 0, 0, 1, 1, 2, 2, 3, 3};
__constant__ int c_PJ[9] = {1, 2, 3, 2, 3, 1, 3, 1, 2};

__device__ inline float loadF(float* p) {
    return __hip_atomic_load(p, __ATOMIC_RELAXED, __HIP_MEMORY_SCOPE_AGENT);
}

// block-wide sum for 1024 threads (16 waves): wave shuffle + 16-slot LDS
__device__ inline float blockSum16(float v, float* tmp16) {
    #pragma unroll
    for (int off = 32; off > 0; off >>= 1) v += __shfl_down(v, off);
    if ((threadIdx.x & 63) == 0) tmp16[threadIdx.x >> 6] = v;
    __syncthreads();
    float s = 0.f;
    #pragma unroll
    for (int w = 0; w < 16; ++w) s += tmp16[w];
    __syncthreads();
    return s;
}

// ---------------------------------------------------------------------------
// k_pair (256 threads)  [round-10 verified structure]
//   blocks [0,132):  gram tiles split over t: (tile, t-half); float4 loads;
//                    G_half[a,b,d] = sum_{t in half} Za[t,d]*Zb[t,d]
//   blocks [132,252): sd[p] = sum_t ||X[p,t]-Y[p,t]||^2  (softdtw collapses
//                    to the diagonal: BANDWIDTH=0.1 keeps only i==j)
//   block 0 thread 0 zeroes k_mmd3's completion counter (kernel-boundary
//   ordered).
// ---------------------------------------------------------------------------
__global__ __launch_bounds__(256) void k_pair(const float* __restrict__ data,
                                              const float* __restrict__ teacher,
                                              float* __restrict__ sd,   // 120
                                              float* __restrict__ G0,   // 44*44*64
                                              float* __restrict__ G1,   // 44*44*64
                                              unsigned* __restrict__ counter)
{
    const int b = blockIdx.x;
    const int tid = threadIdx.x;

    __shared__ float red2[16][16][DF];   // 64 KB (gram branch)
    __shared__ float redS[256];          // 1 KB  (sd branch)

    if (b == 0 && tid == 0) *counter = 0u;

    if (b < 132) {
        const int tile = b >> 1, half = b & 1;
        int q = tile, ta = 0;
        while (q >= 11 - ta) { q -= 11 - ta; ta++; }
        const int tb = ta + q;
        const int ty = tid >> 4, dq = tid & 15;     // 16x16 threads
        const int ua0 = ta * 4, ub0 = tb * 4;

        const float4* rA[4];
        const float4* rB[4];
        #pragma unroll
        for (int i = 0; i < 4; ++i) {
            const int ua = ua0 + i, ub = ub0 + i;
            rA[i] = (const float4*)(data + (size_t)((ua / 11) * STEP_ + (ua % 11)) * ROW_ELEMS);
            rB[i] = (const float4*)(data + (size_t)((ub / 11) * STEP_ + (ub % 11)) * ROW_ELEMS);
        }

        float acc[4][4][4];
        #pragma unroll
        for (int i = 0; i < 4; ++i)
            #pragma unroll
            for (int j = 0; j < 4; ++j)
                #pragma unroll
                for (int c = 0; c < 4; ++c) acc[i][j][c] = 0.f;

        const int tbase = half * 256 + ty;           // t-half, stride 16
        #pragma unroll 2
        for (int it = 0; it < 16; ++it) {
            const int t = tbase + it * 16;
            float4 av[4], bv[4];
            #pragma unroll
            for (int i = 0; i < 4; ++i) av[i] = rA[i][t * 16 + dq];
            #pragma unroll
            for (int j = 0; j < 4; ++j) bv[j] = rB[j][t * 16 + dq];
            #pragma unroll
            for (int i = 0; i < 4; ++i)
                #pragma unroll
                for (int j = 0; j < 4; ++j) {
                    acc[i][j][0] += av[i].x * bv[j].x;
                    acc[i][j][1] += av[i].y * bv[j].y;
                    acc[i][j][2] += av[i].z * bv[j].z;
                    acc[i][j][3] += av[i].w * bv[j].w;
                }
        }

        #pragma unroll
        for (int i = 0; i < 4; ++i)
            #pragma unroll
            for (int j = 0; j < 4; ++j)
                *(float4*)&red2[ty][i * 4 + j][dq * 4] =
                    make_float4(acc[i][j][0], acc[i][j][1], acc[i][j][2], acc[i][j][3]);
        __syncthreads();

        float* __restrict__ Gh = half ? G1 : G0;
        for (int o = tid; o < 1024; o += 256) {
            const int ij = o >> 6, d = o & 63;
            float s = 0.f;
            #pragma unroll
            for (int t2 = 0; t2 < 16; ++t2) s += red2[t2][ij][d];
            const int ua = ua0 + (ij >> 2), ub = ub0 + (ij & 3);
            Gh[(size_t)ua * GSTRIDE + ub * DF + d] = s;
            Gh[(size_t)ub * GSTRIDE + ua * DF + d] = s;   // same value on diag tiles
        }
    } else {
        const int bb = b - 132;                  // 0..119
        const float* src = (bb < 60) ? data : teacher;
        const int p = bb % 60;
        const int w = p / 15, k = p % 15;
        const float4* A = (const float4*)(src + (size_t)(w * STEP_) * ROW_ELEMS);
        const float4* O = (const float4*)(src + (size_t)(w * STEP_ + 1 + k) * ROW_ELEMS);
        float acc = 0.f;
        #pragma unroll 4
        for (int i = tid; i < ROW_ELEMS / 4; i += 256) {
            float4 a = A[i], o = O[i];
            float dx = a.x - o.x, dy = a.y - o.y, dz = a.z - o.z, dw = a.w - o.w;
            acc += dx * dx + dy * dy + dz * dz + dw * dw;
        }
        redS[tid] = acc;
        __syncthreads();
        for (int s = 128; s > 0; s >>= 1) {
            if (tid < s) redS[tid] += redS[tid + s];
            __syncthreads();
        }
        if (tid == 0) sd[bb] = redS[0];
    }
}

// ---------------------------------------------------------------------------
// k_mmd3: ONE block per pair (9 blocks x 1024 threads). bw computed once per
//   pair (124 KB read), then all 22 rows of the signed 5-scale RBF sum in the
//   same block. ~2.3 MB total G traffic (was 25 MB with per-row blocks).
//   Last block (completion counter, zeroed by k_pair) runs the triplet
//   finisher and writes out[0].
// ---------------------------------------------------------------------------
__global__ __launch_bounds__(1024) void k_mmd3(const float* __restrict__ G0,
                                               const float* __restrict__ G1,
                                               float* __restrict__ sd,     // 120
                                               const int* __restrict__ lens,
                                               float* __restrict__ mmd9,   // 9
                                               unsigned* __restrict__ counter,
                                               float* __restrict__ out)
{
    const int blk = blockIdx.x;      // 0..8 = pair
    const int tid = threadIdx.x;
    const int gi = c_PI[blk], gj = c_PJ[blk];

    __shared__ float diagT[22 * DF];   // 5.5 KB
    __shared__ float tmp16[16];
    __shared__ float mmd9l[9];
    __shared__ float sdl[120];
    __shared__ int lastFlag;

    // ---- diag rows (summed halves) into LDS
    for (int e = tid; e < 22 * DF; e += 1024) {
        const int bb = e >> 6, d2 = e & 63;
        const int ub = (bb < 11) ? gi * 11 + bb : gj * 11 + bb - 11;
        const size_t off = (size_t)ub * GSTRIDE + ub * DF + d2;
        diagT[e] = G0[off] + G1[off];
    }

    // ---- phase A: full-pair gram sum (22 rows x 2 contiguous 11*64 spans)
    const float4* G0q = (const float4*)G0;
    const float4* G1q = (const float4*)G1;
    float gs = 0.f;
    for (int e = tid; e < 7744; e += 1024) {
        const int f4 = e % 176;
        const int sp = (e / 176) & 1;
        const int a2 = e / 352;
        const int ua = (a2 < 11) ? gi * 11 + a2 : gj * 11 + a2 - 11;
        const int colbase = (sp ? gj : gi) * 11 * DF;
        const size_t qi = ((size_t)ua * GSTRIDE + colbase) / 4 + f4;
        const float4 v0 = G0q[qi], v1 = G1q[qi];
        gs += (v0.x + v1.x) + (v0.y + v1.y) + (v0.z + v1.z) + (v0.w + v1.w);
    }
    __syncthreads();   // diagT ready

    float dsp = 0.f;
    for (int e = tid; e < 22 * DF; e += 1024) dsp += diagT[e];

    const float sumG    = blockSum16(gs,  tmp16);
    const float diagSum = blockSum16(dsp, tmp16);

    // sum L2 over pair = 44*diagSum - 2*sumG ; bw = sumL2/(462*4)
    const float bw = (44.f * diagSum - 2.f * sumG) / (462.f * 4.f);
    const float inv0 = 1.f / bw;

    // ---- phase B: all 22 rows, float4 over d: 22*(22*16) = 7744 iters
    const float4* dTq = (const float4*)diagT;
    float s2 = 0.f;
    for (int e = tid; e < 7744; e += 1024) {
        const int aa = e / 352;                   // row of pair
        const int rest = e % 352;
        const int bb = rest >> 4, dq = rest & 15;
        const int ua = (aa < 11) ? gi * 11 + aa : gj * 11 + aa - 11;
        const int ub = (bb < 11) ? gi * 11 + bb : gj * 11 + bb - 11;
        const size_t ci = ((size_t)ua * GSTRIDE) / 4 + ub * 16 + dq;
        const float4 c0 = G0q[ci], c1 = G1q[ci];
        const float4 dB = dTq[bb * 16 + dq];
        const float4 dA = dTq[aa * 16 + dq];
        float l2[4];
        l2[0] = dA.x + dB.x - 2.f * (c0.x + c1.x);
        l2[1] = dA.y + dB.y - 2.f * (c0.y + c1.y);
        l2[2] = dA.z + dB.z - 2.f * (c0.z + c1.z);
        l2[3] = dA.w + dB.w - 2.f * (c0.w + c1.w);
        float kv = 0.f;
        #pragma unroll
        for (int c = 0; c < 4; ++c) {
            float inv = inv0;
            #pragma unroll
            for (int ii = 0; ii < 5; ++ii) { kv += __expf(-l2[c] * inv); inv *= 0.5f; }
        }
        s2 += (((aa < 11) == (bb < 11)) ? kv : -kv);
    }
    const float pairSum = blockSum16(s2, tmp16);

    // ---- completion protocol (round-7 verified pattern)
    if (tid == 0) {
        mmd9[blk] = pairSum / (121.f * 64.f);
        __threadfence();
        const unsigned old = atomicAdd(counter, 1u);
        lastFlag = (old == 8u);
    }
    __syncthreads();
    if (!lastFlag) return;

    // ---- finisher (last pair-block only)
    if (tid < 9)   mmd9l[tid] = loadF(&mmd9[tid]);   // coherent reads
    if (tid < 120) sdl[tid]  = sd[tid];              // written by k_pair (prev kernel)
    __syncthreads();

    if (tid == 0) {
        float total = 0.f;
        for (int w = 0; w < 4; ++w) {
            float ds[15], dt[15];
            for (int k = 0; k < 15; ++k) {
                const float denom = (float)lens[w * STEP_] + (float)lens[w * STEP_ + 1 + k];
                ds[k] = sdl[w * 15 + k] / denom;
                dt[k] = sdl[60 + w * 15 + k] / denom;
            }
            float mx = 0.f;
            for (int i = 0; i < 10; ++i)
                for (int j = 0; j < 5; ++j) {
                    float v = dt[5 + i] - dt[j];
                    v = v > 0.f ? v : 0.f;
                    mx = fmaxf(mx, v);
                }
            const float scale = (1.0f - 0.1f) / mx;
            float sum_lk = 0.f, nz = 0.f;
            for (int i = 0; i < 10; ++i)
                for (int j = 0; j < 5; ++j) {
                    float v = dt[5 + i] - dt[j];
                    v = v > 0.f ? v : 0.f;
                    const float fd = scale * v + 0.1f;
                    float lk = ds[j] - ds[5 + i] + fd;
                    lk = lk > 0.f ? lk : 0.f;
                    sum_lk += lk;
                    if (lk != 0.f) nz += 1.f;
                }
            const float lv = sum_lk / (nz + 1.f);
            const float ca = (ds[0] + ds[1] + ds[2] + ds[3] + ds[4]) * 0.2f;
            const float cb = (ds[5] + ds[6] + ds[7] + ds[8] + ds[9]) * 0.2f;
            const float intra = (ds[0] - ca) + (ds[1] - ca) + (ds[2] - ca) + (ds[3] - ca) + (ds[4] - ca);
            float inter = 1.0f - fabsf(ca - cb);
            inter = inter > 0.f ? inter : 0.f;
            total += lv + intra * 0.1f + inter * 0.1f;
        }
        total *= 0.25f;

        float mmax = 0.f;   // padded zero slot in mmds
        for (int q2 = 0; q2 < 9; ++q2) mmax = fmaxf(mmax, mmd9l[q2]);
        out[0] = total + 0.5f * mmax;
    }
}

// ---------------------------------------------------------------------------
extern "C" void kernel_launch(void* const* d_in, const int* in_sizes, int n_in,
                              void* d_out, int out_size, void* d_ws, size_t ws_size,
                              hipStream_t stream) {
    const float* data    = (const float*)d_in[0];
    const int*   lens    = (const int*)d_in[1];
    const float* teacher = (const float*)d_in[2];
    float* out = (float*)d_out;

    float*    sd      = (float*)d_ws;                    // 120 (pad 128)
    float*    G0      = sd + 128;                        // 123904
    float*    G1      = G0 + (size_t)NROWS_G * GSTRIDE;  // 123904
    float*    mmd9    = G1 + (size_t)NROWS_G * GSTRIDE;  // 9 (pad 16)
    unsigned* counter = (unsigned*)(mmd9 + 16);          // 1

    k_pair<<<252, 256, 0, stream>>>(data, teacher, sd, G0, G1, counter);
    k_mmd3<<<9, 1024, 0, stream>>>(G0, G1, sd, lens, mmd9, counter, out);
}